// Round 6
// baseline (750.006 us; speedup 1.0000x reference)
//
#include <hip/hip_runtime.h>

typedef float  f32x4  __attribute__((ext_vector_type(4)));
typedef short  bf16x8 __attribute__((ext_vector_type(8)));
typedef unsigned int   u32;
typedef unsigned short u16;

#define N_NODES 30000
#define N_EDGES 480000
#define VOCABSZ 10000
#define LOG2E 1.442695040888963f

__device__ __forceinline__ float sigm(float x){
  return __builtin_amdgcn_rcpf(1.f + __builtin_amdgcn_exp2f(-LOG2E*x));
}
__device__ __forceinline__ float tanh_(float x){
  return 1.f - 2.f*__builtin_amdgcn_rcpf(1.f + __builtin_amdgcn_exp2f((2.f*LOG2E)*x));
}
__device__ __forceinline__ u16 f2bf(float f){   // round-to-nearest-even bf16
  u32 u = __builtin_bit_cast(u32, f);
  u = u + 0x7fffu + ((u>>16)&1u);
  return (u16)(u>>16);
}

// ---------------------------------------------------------------------------
// W_r = sum_b wcomp[r,b] * basis[b]  -> stored [r][i][o] f32 (GEMM-B layout)
// ---------------------------------------------------------------------------
__global__ __launch_bounds__(256) void wmat_kernel(
    const float* __restrict__ b0, const float* __restrict__ c0,
    const float* __restrict__ b1, const float* __restrict__ c1,
    const float* __restrict__ b2, const float* __restrict__ c2,
    float* __restrict__ W0, float* __restrict__ W1, float* __restrict__ W2)
{
  int id = blockIdx.x*256 + threadIdx.x;
  if (id < 32768){
    int r = id>>12;
    float s = 0.f;
    #pragma unroll
    for (int b=0;b<4;++b) s += c0[r*4+b]*b0[b*4096 + (id&4095)];
    W0[id] = s;
  } else if (id < 65536){
    int k = id - 32768;
    int r = k>>12;
    float s = 0.f;
    #pragma unroll
    for (int b=0;b<4;++b) s += c1[r*4+b]*b1[b*4096 + (k&4095)];
    W1[k] = s;
  } else if (id < 73728){
    int k = id - 65536;
    int r = k>>10;
    float s = 0.f;
    #pragma unroll
    for (int b=0;b<4;++b) s += c2[r*4+b]*b2[b*1024 + (k&1023)];
    W2[k] = s;
  }
}

// ---------------------------------------------------------------------------
// emb f32 [10000][128] -> bf16 [10000][128]  (2.56 MB, L2-resident)
// ---------------------------------------------------------------------------
__global__ __launch_bounds__(256) void ebf_kernel(
    const float* __restrict__ emb, u16* __restrict__ ebf)
{
  int id = blockIdx.x*256 + threadIdx.x;      // 0..319999, 4 elems each
  if (id < 320000){
    f32x4 v = *(const f32x4*)(emb + (size_t)id*4);
    u16 o0 = f2bf(v[0]), o1 = f2bf(v[1]), o2 = f2bf(v[2]), o3 = f2bf(v[3]);
    u32 lo = (u32)o0 | ((u32)o1<<16);
    u32 hi = (u32)o2 | ((u32)o3<<16);
    uint2 pk; pk.x = lo; pk.y = hi;
    *(uint2*)(ebf + (size_t)id*4) = pk;
  }
}

// ---------------------------------------------------------------------------
// Fused 32-step reverse LSTM + fc epilogue.  64 nodes/block, 8 waves, grid 469.
// Both W_ih and W_hh live in registers as MFMA A-frags; per step:
//   x rows (bf16, 256B) coop-staged from L2-resident ebf into swizzled LDS,
//   z = W_hh@h + W_ih@x via 32 MFMA, +f32 bias, gates on VALU.
// h: bf16 XOR-swizzled dbuf LDS.  x: staged 1 step ahead (T14 split).
// ---------------------------------------------------------------------------
__global__ __launch_bounds__(512, 2) void lstm_kernel(
    const int* __restrict__ tok, const u16* __restrict__ ebf,
    const float* __restrict__ w_ih, const float* __restrict__ w_hh,
    const float* __restrict__ b_ih, const float* __restrict__ b_hh,
    const float* __restrict__ fc_w, const float* __restrict__ fc_b,
    float* __restrict__ feats)
{
  __shared__ __align__(16) char lds[32768];     // h double buffer (16KB x2)
  __shared__ __align__(16) char xld[32768];     // x double buffer (16KB x2)
  __shared__ u16 tokL[64*33];
  const int tid = threadIdx.x;
  const int wave = tid>>6, lane = tid&63;
  const int c16 = lane&15, g4 = lane>>4;
  const int nb = blockIdx.x*64;

  // persistent A-frags: j = g*128 + wave*16 + c16 ; k = kk*32 + 8*g4 + i
  bf16x8 ahh[4][4], aih[4][4];
  #pragma unroll
  for (int g=0; g<4; ++g){
    const float* wrh = w_hh + (g*128 + wave*16 + c16)*128 + g4*8;
    const float* wri = w_ih + (g*128 + wave*16 + c16)*128 + g4*8;
    #pragma unroll
    for (int kk=0; kk<4; ++kk){
      f32x4 ha = *(const f32x4*)(wrh + kk*32);
      f32x4 hb = *(const f32x4*)(wrh + kk*32 + 4);
      f32x4 ia = *(const f32x4*)(wri + kk*32);
      f32x4 ib = *(const f32x4*)(wri + kk*32 + 4);
      bf16x8 a, b;
      a[0]=(short)f2bf(ha[0]); a[1]=(short)f2bf(ha[1]);
      a[2]=(short)f2bf(ha[2]); a[3]=(short)f2bf(ha[3]);
      a[4]=(short)f2bf(hb[0]); a[5]=(short)f2bf(hb[1]);
      a[6]=(short)f2bf(hb[2]); a[7]=(short)f2bf(hb[3]);
      b[0]=(short)f2bf(ia[0]); b[1]=(short)f2bf(ia[1]);
      b[2]=(short)f2bf(ia[2]); b[3]=(short)f2bf(ia[3]);
      b[4]=(short)f2bf(ib[0]); b[5]=(short)f2bf(ib[1]);
      b[6]=(short)f2bf(ib[2]); b[7]=(short)f2bf(ib[3]);
      ahh[g][kk] = a; aih[g][kk] = b;
    }
  }
  // f32 bias per lane: j = g*128 + wave*16 + g4*4 + q
  float bias[4][4];
  #pragma unroll
  for (int g=0; g<4; ++g)
    #pragma unroll
    for (int q=0; q<4; ++q){
      int j = g*128 + wave*16 + g4*4 + q;
      bias[g][q] = b_ih[j] + b_hh[j];
    }

  { // zero h buffer 0 (16KB)
    f32x4 z = {0.f,0.f,0.f,0.f};
    for (int i = tid*16; i < 16384; i += 8192) *(f32x4*)(lds + i) = z;
  }
  { // stage tokens as u16: tokL[n][33] (padded)
    int n = tid>>3, t0 = (tid&7)*4;
    int node = nb + n; if (node > N_NODES-1) node = N_NODES-1;
    int4 a = *(const int4*)(tok + node*32 + t0);
    tokL[n*33 + t0    ] = (u16)a.x;
    tokL[n*33 + t0 + 1] = (u16)a.y;
    tokL[n*33 + t0 + 2] = (u16)a.z;
    tokL[n*33 + t0 + 3] = (u16)a.w;
  }
  __syncthreads();

  // x staging geometry: thread -> (row 0..63, 32B segment 0..7), swizzled dest
  const int srow = tid>>3, sseg = tid&7;
  const int sx0 = srow*256 + ((sseg*32)    ^ ((srow&7)<<4));
  const int sx1 = srow*256 + ((sseg*32+16) ^ ((srow&7)<<4));

  { // stage x for t=0 (t'=31) into xld[0]
    int tk = tokL[srow*33 + 31];
    const char* ep = (const char*)ebf + (size_t)tk*256 + sseg*32;
    uint4 a = *(const uint4*)ep;
    uint4 b = *(const uint4*)(ep+16);
    *(uint4*)(xld + sx0) = a;
    *(uint4*)(xld + sx1) = b;
  }

  const int swz = (c16&7)<<4;
  int rb[4];
  #pragma unroll
  for (int kk=0;kk<4;++kk) rb[kk] = c16*256 + ((kk*64 + g4*16)^swz);
  const int wbB = c16*256 + ((wave*32 + g4*8)^swz);

  float creg[4][4];
  #pragma unroll
  for (int nt=0;nt<4;++nt)
    #pragma unroll
    for (int q=0;q<4;++q) creg[nt][q]=0.f;

  __syncthreads();

  for (int t=0; t<32; ++t){
    const int bufR = (t&1)<<14, bufW = bufR ^ 16384;
    char* xcur = xld + ((t&1)<<14);
    char* xnxt = xld + (((t+1)&1)<<14);
    // issue next-step x loads early (hide under compute)
    uint4 sa, sb;
    if (t < 31){
      int tk = tokL[srow*33 + 30 - t];
      const char* ep = (const char*)ebf + (size_t)tk*256 + sseg*32;
      sa = *(const uint4*)ep;
      sb = *(const uint4*)(ep+16);
    }
    #pragma unroll
    for (int nt=0; nt<4; ++nt){
      bf16x8 bfr[4], bx[4];
      #pragma unroll
      for (int kk=0;kk<4;++kk){
        bfr[kk] = *(const bf16x8*)(lds + bufR + rb[kk] + nt*4096);
        bx[kk]  = *(const bf16x8*)(xcur + rb[kk] + nt*4096);
      }
      f32x4 acc[4];
      #pragma unroll
      for (int g=0;g<4;++g){ acc[g][0]=0.f; acc[g][1]=0.f; acc[g][2]=0.f; acc[g][3]=0.f; }
      #pragma unroll
      for (int kk=0;kk<4;++kk){
        acc[0] = __builtin_amdgcn_mfma_f32_16x16x32_bf16(ahh[0][kk], bfr[kk], acc[0], 0,0,0);
        acc[1] = __builtin_amdgcn_mfma_f32_16x16x32_bf16(ahh[1][kk], bfr[kk], acc[1], 0,0,0);
        acc[2] = __builtin_amdgcn_mfma_f32_16x16x32_bf16(ahh[2][kk], bfr[kk], acc[2], 0,0,0);
        acc[3] = __builtin_amdgcn_mfma_f32_16x16x32_bf16(ahh[3][kk], bfr[kk], acc[3], 0,0,0);
      }
      #pragma unroll
      for (int kk=0;kk<4;++kk){
        acc[0] = __builtin_amdgcn_mfma_f32_16x16x32_bf16(aih[0][kk], bx[kk], acc[0], 0,0,0);
        acc[1] = __builtin_amdgcn_mfma_f32_16x16x32_bf16(aih[1][kk], bx[kk], acc[1], 0,0,0);
        acc[2] = __builtin_amdgcn_mfma_f32_16x16x32_bf16(aih[2][kk], bx[kk], acc[2], 0,0,0);
        acc[3] = __builtin_amdgcn_mfma_f32_16x16x32_bf16(aih[3][kk], bx[kk], acc[3], 0,0,0);
      }
      float hv[4];
      #pragma unroll
      for (int q=0;q<4;++q){          // gates: i,f,g,o
        float zi=acc[0][q]+bias[0][q], zf=acc[1][q]+bias[1][q];
        float zg=acc[2][q]+bias[2][q], zo=acc[3][q]+bias[3][q];
        float cn = sigm(zf)*creg[nt][q] + sigm(zi)*tanh_(zg);
        creg[nt][q] = cn;
        hv[q] = sigm(zo)*tanh_(cn);
      }
      u32 plo, phi;
      asm("v_cvt_pk_bf16_f32 %0, %1, %2" : "=v"(plo) : "v"(hv[0]), "v"(hv[1]));
      asm("v_cvt_pk_bf16_f32 %0, %1, %2" : "=v"(phi) : "v"(hv[2]), "v"(hv[3]));
      uint2 hw; hw.x = plo; hw.y = phi;
      *(uint2*)(lds + bufW + wbB + nt*4096) = hw;
    }
    if (t < 31){                      // late write of staged x (T14)
      *(uint4*)(xnxt + sx0) = sa;
      *(uint4*)(xnxt + sx1) = sb;
    }
    __syncthreads();
  }
  // fc epilogue: final h in buffer 0; wave pair handles node-tile wave>>1,
  // each half covers 2 of the 4 output tiles.
  const int w2 = wave>>1, half = wave&1;
  f32x4 fca[2];
  #pragma unroll
  for (int oi=0;oi<2;++oi){ fca[oi][0]=0.f; fca[oi][1]=0.f; fca[oi][2]=0.f; fca[oi][3]=0.f; }
  #pragma unroll
  for (int kk=0;kk<4;++kk){
    bf16x8 b = *(const bf16x8*)(lds + rb[kk] + w2*4096);
    #pragma unroll
    for (int oi=0;oi<2;++oi){
      int ot = half*2 + oi;
      const float* fr = fc_w + (ot*16 + c16)*128 + kk*32 + g4*8;
      f32x4 wa = *(const f32x4*)fr;
      f32x4 wbv = *(const f32x4*)(fr+4);
      bf16x8 a;
      a[0]=(short)f2bf(wa[0]); a[1]=(short)f2bf(wa[1]);
      a[2]=(short)f2bf(wa[2]); a[3]=(short)f2bf(wa[3]);
      a[4]=(short)f2bf(wbv[0]); a[5]=(short)f2bf(wbv[1]);
      a[6]=(short)f2bf(wbv[2]); a[7]=(short)f2bf(wbv[3]);
      fca[oi] = __builtin_amdgcn_mfma_f32_16x16x32_bf16(a, b, fca[oi], 0,0,0);
    }
  }
  const int node = nb + w2*16 + c16;
  if (node < N_NODES){
    #pragma unroll
    for (int oi=0;oi<2;++oi)
      #pragma unroll
      for (int q=0;q<4;++q){
        int o = (half*2+oi)*16 + g4*4 + q;
        feats[node*64 + o] = fca[oi][q] + fc_b[o];
      }
  }
}

// ---------------------------------------------------------------------------
// CSR build: histogram -> block scan -> bucket permutation
// ---------------------------------------------------------------------------
__global__ __launch_bounds__(256) void hist_kernel(
    const int* __restrict__ dst, int* __restrict__ cnt, int n)
{
  int e = blockIdx.x*256 + threadIdx.x;
  if (e < n) atomicAdd(&cnt[dst[e]], 1);
}

__global__ __launch_bounds__(1024) void scan_kernel(
    int* __restrict__ cnt, int* __restrict__ ofs)   // cnt doubles as "cur"
{
  __shared__ int sums[1024];
  const int tid = threadIdx.x;
  const int base = tid*30;                          // 1024*30 = 30720 >= 30001
  int loc[30]; int s = 0;
  #pragma unroll
  for (int i=0;i<30;++i){
    int d = base + i;
    int c = (d < N_NODES) ? cnt[d] : 0;
    loc[i] = s; s += c;
  }
  sums[tid] = s;
  __syncthreads();
  for (int off=1; off<1024; off<<=1){
    int v = (tid >= off) ? sums[tid-off] : 0;
    __syncthreads();
    sums[tid] += v;
    __syncthreads();
  }
  int excl = sums[tid] - s;
  #pragma unroll
  for (int i=0;i<30;++i){
    int d = base + i;
    if (d <= N_NODES){
      int v = excl + loc[i];
      ofs[d] = v;
      if (d < N_NODES) cnt[d] = v;                  // reset cur = segment start
    }
  }
}

__global__ __launch_bounds__(256) void permute_kernel(
    const int* __restrict__ dst, int* __restrict__ cur,
    int* __restrict__ perm, int n)
{
  int e = blockIdx.x*256 + threadIdx.x;
  if (e < n){
    int p = atomicAdd(&cur[dst[e]], 1);
    perm[p] = e;
  }
}

// ---------------------------------------------------------------------------
// RGCN transform-first: tmp[n][r*NO+o] = (relu? h[n]) @ W_r   (K=64, f32)
// block 256 thr, tile 64 nodes x 128 cols; grid (469, 8*NO/128)
// ---------------------------------------------------------------------------
template<int NO, bool RELU>
__global__ __launch_bounds__(256) void transform_kernel(
    const float* __restrict__ h, const float* __restrict__ W,
    float* __restrict__ tmp, int n_nodes)
{
  __shared__ float As[64][68];
  __shared__ float Bs[64][132];
  const int tid = threadIdx.x;
  const int n0 = blockIdx.x*64;
  const int j0 = blockIdx.y*128;
  constexpr int WIDTH = 8*NO;

  for (int idx = tid*4; idx < 4096; idx += 1024){
    int r = idx>>6, c = idx&63;
    int n = n0 + r; if (n > n_nodes-1) n = n_nodes-1;
    f32x4 v = *(const f32x4*)(h + (size_t)n*64 + c);
    if (RELU){
      v[0]=fmaxf(v[0],0.f); v[1]=fmaxf(v[1],0.f);
      v[2]=fmaxf(v[2],0.f); v[3]=fmaxf(v[3],0.f);
    }
    *(f32x4*)&As[r][c] = v;
  }
  for (int idx = tid*4; idx < 8192; idx += 1024){
    int k = idx>>7, j = idx&127;
    int jj = j0 + j;
    int r = jj / NO, o = jj & (NO-1);
    f32x4 v = *(const f32x4*)(W + r*(64*NO) + k*NO + o);
    *(f32x4*)&Bs[k][j] = v;
  }
  __syncthreads();

  const int tx = tid&15, ty = tid>>4;   // 8 cols x 4 nodes per thread
  float acc[4][8];
  #pragma unroll
  for (int i=0;i<4;++i)
    #pragma unroll
    for (int j=0;j<8;++j) acc[i][j]=0.f;

  #pragma unroll 4
  for (int k=0;k<64;++k){
    f32x4 b0 = *(const f32x4*)&Bs[k][tx*8];
    f32x4 b1 = *(const f32x4*)&Bs[k][tx*8+4];
    #pragma unroll
    for (int i=0;i<4;++i){
      float a = As[ty*4+i][k];
      #pragma unroll
      for (int j=0;j<4;++j){
        acc[i][j]   += a*b0[j];
        acc[i][j+4] += a*b1[j];
      }
    }
  }
  #pragma unroll
  for (int i=0;i<4;++i){
    int n = n0 + ty*4 + i;
    if (n < n_nodes){
      *(f32x4*)(tmp + (size_t)n*WIDTH + j0 + tx*8)     = *(f32x4*)&acc[i][0];
      *(f32x4*)(tmp + (size_t)n*WIDTH + j0 + tx*8 + 4) = *(f32x4*)&acc[i][4];
    }
  }
}

// ---------------------------------------------------------------------------
// CSR gather-reduce: out[d][:NO] = sum over edges e with dst==d of
//   enorm[e] * tmp[src[e]][rel[e]][:NO]      (no atomics, coalesced writes)
// NO=64: wave per dst.  NO=16: 4 dsts per wave (16-lane groups).
// ---------------------------------------------------------------------------
template<int NO>
__global__ __launch_bounds__(256) void gather_kernel(
    const float* __restrict__ tmp, const int* __restrict__ perm,
    const int* __restrict__ ofs, const int* __restrict__ src,
    const int* __restrict__ rel, const float* __restrict__ enorm,
    float* __restrict__ out)
{
  constexpr int WIDTH = 8*NO;
  const int lane = threadIdx.x & 63;
  const int wid = (blockIdx.x*256 + threadIdx.x) >> 6;
  int d, o;
  if (NO == 64){ d = wid; o = lane; }
  else         { d = wid*4 + (lane>>4); o = lane & 15; }
  if (d >= N_NODES) return;
  const int beg = ofs[d], end = ofs[d+1];
  float acc = 0.f;
  if (beg < end){
    int pe = perm[beg];
    int s = src[pe], r = rel[pe]; float nm = enorm[pe];
    for (int i = beg; i < end; ){
      float v = tmp[(size_t)s*WIDTH + r*NO + o];
      ++i;
      int s1=0, r1=0; float nm1=0.f;
      if (i < end){
        int pe1 = perm[i];
        s1 = src[pe1]; r1 = rel[pe1]; nm1 = enorm[pe1];
      }
      acc += nm * v;
      s = s1; r = r1; nm = nm1;
    }
  }
  out[(size_t)d*NO + o] = acc;
}

// ---------------------------------------------------------------------------
extern "C" void kernel_launch(void* const* d_in, const int* in_sizes, int n_in,
                              void* d_out, int out_size, void* d_ws, size_t ws_size,
                              hipStream_t stream)
{
  const int*   tok    = (const int*)  d_in[0];
  const int*   src    = (const int*)  d_in[2];
  const int*   dst    = (const int*)  d_in[3];
  const int*   rel    = (const int*)  d_in[4];
  const float* enorm  = (const float*)d_in[5];
  const float* emb    = (const float*)d_in[6];
  const float* w_ih   = (const float*)d_in[7];
  const float* w_hh   = (const float*)d_in[8];
  const float* b_ih   = (const float*)d_in[9];
  const float* b_hh   = (const float*)d_in[10];
  const float* fc_w   = (const float*)d_in[11];
  const float* fc_b   = (const float*)d_in[12];
  const float* basis0 = (const float*)d_in[13];
  const float* wcomp0 = (const float*)d_in[14];
  const float* basis1 = (const float*)d_in[15];
  const float* wcomp1 = (const float*)d_in[16];
  const float* basis2 = (const float*)d_in[17];
  const float* wcomp2 = (const float*)d_in[18];

  char* ws = (char*)d_ws;
  // tmp [0, 61.44M); ebf overlaps its head (dead before first transform)
  float* tmp   = (float*)(ws);                 // 61,440,000 B
  u16*   ebf   = (u16*)  (ws);                 //  2,560,000 B (inside tmp)
  float* feats = (float*)(ws + 61440000);      //  7,680,000 B
  // CSR arrays live in the feats region (feats dead after transform layer 0)
  int*   ofs   = (int*)  (ws + 61440000);      //    120,064 B
  int*   cur   = (int*)  (ws + 61560064);      //    120,064 B
  int*   perm  = (int*)  (ws + 61680128);      //  1,920,000 B (ends 63,600,128)
  float* g1    = (float*)(ws + 69120000);      //  7,680,000 B
  float* g2    = (float*)(ws + 76800000);      //  7,680,000 B
  float* W0    = (float*)(ws + 84480000);      //    131,072 B
  float* W1    = (float*)(ws + 84611072);      //    131,072 B
  float* W2    = (float*)(ws + 84742144);      //     32,768 B

  wmat_kernel<<<288, 256, 0, stream>>>(basis0, wcomp0, basis1, wcomp1,
                                       basis2, wcomp2, W0, W1, W2);
  ebf_kernel<<<1250, 256, 0, stream>>>(emb, ebf);
  lstm_kernel<<<469, 512, 0, stream>>>(tok, ebf, w_ih, w_hh, b_ih, b_hh,
                                       fc_w, fc_b, feats);

  // layer 0 transform: feats -> tmp (feats dead afterwards)
  transform_kernel<64,false><<<dim3(469,4), 256, 0, stream>>>(feats, W0, tmp, N_NODES);

  // CSR build (into the now-dead feats region)
  hipMemsetAsync(cur, 0, 120004, stream);
  hist_kernel<<<1875, 256, 0, stream>>>(dst, cur, N_EDGES);
  scan_kernel<<<1, 1024, 0, stream>>>(cur, ofs);
  permute_kernel<<<1875, 256, 0, stream>>>(dst, cur, perm, N_EDGES);

  // layer 0 gather: tmp -> g1
  gather_kernel<64><<<7500, 256, 0, stream>>>(tmp, perm, ofs, src, rel, enorm, g1);

  // layer 1: relu(g1) -> tmp -> g2
  transform_kernel<64,true><<<dim3(469,4), 256, 0, stream>>>(g1, W1, tmp, N_NODES);
  gather_kernel<64><<<7500, 256, 0, stream>>>(tmp, perm, ofs, src, rel, enorm, g2);

  // layer 2: relu(g2) -> tmp -> out
  transform_kernel<16,true><<<dim3(469,1), 256, 0, stream>>>(g2, W2, tmp, N_NODES);
  gather_kernel<16><<<1875, 256, 0, stream>>>(tmp, perm, ofs, src, rel, enorm, (float*)d_out);
}

// Round 7
// 700.314 us; speedup vs baseline: 1.0710x; 1.0710x over previous
//
#include <hip/hip_runtime.h>

typedef float  f32x4  __attribute__((ext_vector_type(4)));
typedef short  bf16x8 __attribute__((ext_vector_type(8)));
typedef unsigned int   u32;
typedef unsigned short u16;

#define N_NODES 30000
#define N_EDGES 480000
#define VOCABSZ 10000
#define LOG2E 1.442695040888963f

__device__ __forceinline__ float sigm(float x){
  return __builtin_amdgcn_rcpf(1.f + __builtin_amdgcn_exp2f(-LOG2E*x));
}
__device__ __forceinline__ float tanh_(float x){
  return 1.f - 2.f*__builtin_amdgcn_rcpf(1.f + __builtin_amdgcn_exp2f((2.f*LOG2E)*x));
}
__device__ __forceinline__ u16 f2bf(float f){   // round-to-nearest-even bf16
  u32 u = __builtin_bit_cast(u32, f);
  u = u + 0x7fffu + ((u>>16)&1u);
  return (u16)(u>>16);
}
__device__ __forceinline__ float bflo(u32 u){ return __builtin_bit_cast(float, u<<16); }
__device__ __forceinline__ float bfhi(u32 u){ return __builtin_bit_cast(float, u & 0xffff0000u); }

// ---------------------------------------------------------------------------
// W_r = sum_b wcomp[r,b] * basis[b]  -> stored [r][i][o] f32 (GEMM-B layout)
// ---------------------------------------------------------------------------
__global__ __launch_bounds__(256) void wmat_kernel(
    const float* __restrict__ b0, const float* __restrict__ c0,
    const float* __restrict__ b1, const float* __restrict__ c1,
    const float* __restrict__ b2, const float* __restrict__ c2,
    float* __restrict__ W0, float* __restrict__ W1, float* __restrict__ W2)
{
  int id = blockIdx.x*256 + threadIdx.x;
  if (id < 32768){
    int r = id>>12;
    float s = 0.f;
    #pragma unroll
    for (int b=0;b<4;++b) s += c0[r*4+b]*b0[b*4096 + (id&4095)];
    W0[id] = s;
  } else if (id < 65536){
    int k = id - 32768;
    int r = k>>12;
    float s = 0.f;
    #pragma unroll
    for (int b=0;b<4;++b) s += c1[r*4+b]*b1[b*4096 + (k&4095)];
    W1[k] = s;
  } else if (id < 73728){
    int k = id - 65536;
    int r = k>>10;
    float s = 0.f;
    #pragma unroll
    for (int b=0;b<4;++b) s += c2[r*4+b]*b2[b*1024 + (k&1023)];
    W2[k] = s;
  }
}

// ---------------------------------------------------------------------------
// emb_proj: bf16 table [v][512] in GATHER-FRIENDLY order:
//   original j = g*128 + w*16 + g4*4 + jl  ->  j' = w*64 + g4*16 + jl*4 + g
// so lane (w,c16,g4) reads its 16 values (4 gates x 4 j) as 32 contiguous B.
// grid (157, 4): blockIdx.y covers 4 of the 16 jt-chunks.
// ---------------------------------------------------------------------------
__global__ __launch_bounds__(256) void embproj_kernel(
    const float* __restrict__ emb, const float* __restrict__ w_ih,
    const float* __restrict__ b_ih, const float* __restrict__ b_hh,
    u16* __restrict__ eproj)
{
  __shared__ float et[64*132];
  __shared__ float wt[32*132];
  const int tid = threadIdx.x;
  const int v0 = blockIdx.x*64;
  const int vq = tid>>4, jq = tid&15;

  for (int idx = tid*4; idx < 64*128; idx += 1024){
    int row = idx>>7, col = idx&127;
    int vr = v0 + row; if (vr > VOCABSZ-1) vr = VOCABSZ-1;
    *(f32x4*)&et[row*132+col] = *(const f32x4*)&emb[vr*128+col];
  }
  for (int jt = blockIdx.y*4; jt < blockIdx.y*4 + 4; ++jt){
    __syncthreads();
    for (int idx = tid*4; idx < 32*128; idx += 1024){
      int row = idx>>7, col = idx&127;
      *(f32x4*)&wt[row*132+col] = *(const f32x4*)&w_ih[(jt*32+row)*128+col];
    }
    __syncthreads();
    float acc[4][2] = {};
    #pragma unroll 4
    for (int k=0;k<128;++k){
      float w0v = wt[(jq*2+0)*132+k];
      float w1v = wt[(jq*2+1)*132+k];
      #pragma unroll
      for (int a=0;a<4;++a){
        float e = et[(vq*4+a)*132+k];
        acc[a][0] += e*w0v;
        acc[a][1] += e*w1v;
      }
    }
    int jb = jt*32 + jq*2;
    float bi0 = b_ih[jb]   + b_hh[jb];
    float bi1 = b_ih[jb+1] + b_hh[jb+1];
    // j -> j' mapping (jb even => second value lands at j'+4)
    int g  = jb>>7, rem = jb&127;
    int w  = rem>>4, q4 = (rem>>2)&3, jl = rem&3;
    int jp = w*64 + q4*16 + jl*4 + g;
    #pragma unroll
    for (int a=0;a<4;++a){
      int v = v0 + vq*4 + a;
      if (v < VOCABSZ){
        eproj[v*512 + jp]     = f2bf(acc[a][0]+bi0);
        eproj[v*512 + jp + 4] = f2bf(acc[a][1]+bi1);
      }
    }
  }
}

// ---------------------------------------------------------------------------
// Fused 32-step reverse LSTM + fc epilogue.  32 nodes/block, 8 waves, grid 938.
// (512,4): target 2 blocks/CU (16 waves/CU).  Per-wave state kept < 128
// combined VGPR+AGPR: nt=2, gather prefetch 16 regs, per-kk B-frag loads.
// h: bf16 XOR-swizzled dbuf LDS (8KB x2).  Rolling full-step gather prefetch.
// ---------------------------------------------------------------------------
__global__ __launch_bounds__(512, 4) void lstm_kernel(
    const int* __restrict__ tok, const u16* __restrict__ eproj,
    const float* __restrict__ w_hh, const float* __restrict__ fc_w,
    const float* __restrict__ fc_b, float* __restrict__ feats)
{
  __shared__ __align__(16) char lds[16384];     // h dbuf: 2 x (2 tiles x 4096)
  __shared__ u16 tokL[32*33];
  const int tid = threadIdx.x;
  const int wave = tid>>6, lane = tid&63;
  const int c16 = lane&15, g4 = lane>>4;
  const int nb = blockIdx.x*32;

  // persistent w_hh A-fragments: j = g*128 + wave*16 + c16 ; k = kk*32+8*g4+i
  bf16x8 afr[4][4];
  #pragma unroll
  for (int g=0; g<4; ++g){
    const float* wr = w_hh + (g*128 + wave*16 + c16)*128 + g4*8;
    #pragma unroll
    for (int kk=0; kk<4; ++kk){
      f32x4 wa = *(const f32x4*)(wr + kk*32);
      f32x4 wbv = *(const f32x4*)(wr + kk*32 + 4);
      bf16x8 a;
      a[0]=(short)f2bf(wa[0]); a[1]=(short)f2bf(wa[1]);
      a[2]=(short)f2bf(wa[2]); a[3]=(short)f2bf(wa[3]);
      a[4]=(short)f2bf(wbv[0]); a[5]=(short)f2bf(wbv[1]);
      a[6]=(short)f2bf(wbv[2]); a[7]=(short)f2bf(wbv[3]);
      afr[g][kk] = a;
    }
  }
  { // zero h buffer 0 (8KB): 512 thr x 16B
    f32x4 z = {0.f,0.f,0.f,0.f};
    *(f32x4*)(lds + tid*16) = z;
  }
  if (tid < 256){ // stage tokens as u16: tokL[n][33] (padded)
    int n = tid>>3, t0 = (tid&7)*4;
    int node = nb + n; if (node > N_NODES-1) node = N_NODES-1;
    int4 a = *(const int4*)(tok + node*32 + t0);
    tokL[n*33 + t0    ] = (u16)a.x;
    tokL[n*33 + t0 + 1] = (u16)a.y;
    tokL[n*33 + t0 + 2] = (u16)a.z;
    tokL[n*33 + t0 + 3] = (u16)a.w;
  }
  const int swz = (c16&7)<<4;
  int rb[4];
  #pragma unroll
  for (int kk=0;kk<4;++kk) rb[kk] = c16*256 + ((kk*64 + g4*16)^swz);
  const int wbB = c16*256 + ((wave*32 + g4*8)^swz);

  float creg[2][4];
  #pragma unroll
  for (int nt=0;nt<2;++nt)
    #pragma unroll
    for (int q=0;q<4;++q) creg[nt][q]=0.f;

  __syncthreads();

  const size_t gbase = (size_t)(wave*128 + g4*32);
  uint4 gxX[2], gxY[2];
  #pragma unroll
  for (int nt=0;nt<2;++nt){                 // initial gathers (t=0, t'=31)
    int ptok = tokL[(nt*16+c16)*33 + 31];
    const char* ep = (const char*)eproj + (size_t)ptok*1024 + gbase;
    gxX[nt] = *(const uint4*)ep;
    gxY[nt] = *(const uint4*)(ep+16);
  }

  for (int t=0; t<32; ++t){
    const int bufR = (t&1)<<13, bufW = bufR ^ 8192;
    #pragma unroll
    for (int nt=0; nt<2; ++nt){
      uint4 X = gxX[nt], Y = gxY[nt];
      f32x4 acc[4];
      acc[0][0]=bflo(X.x); acc[1][0]=bfhi(X.x); acc[2][0]=bflo(X.y); acc[3][0]=bfhi(X.y);
      acc[0][1]=bflo(X.z); acc[1][1]=bfhi(X.z); acc[2][1]=bflo(X.w); acc[3][1]=bfhi(X.w);
      acc[0][2]=bflo(Y.x); acc[1][2]=bfhi(Y.x); acc[2][2]=bflo(Y.y); acc[3][2]=bfhi(Y.y);
      acc[0][3]=bflo(Y.z); acc[1][3]=bfhi(Y.z); acc[2][3]=bflo(Y.w); acc[3][3]=bfhi(Y.w);
      if (t < 31){                          // rolling prefetch: next step, same nt
        int ptok = tokL[(nt*16+c16)*33 + 30 - t];
        const char* ep = (const char*)eproj + (size_t)ptok*1024 + gbase;
        gxX[nt] = *(const uint4*)ep;
        gxY[nt] = *(const uint4*)(ep+16);
      }
      #pragma unroll
      for (int kk=0;kk<4;++kk){             // per-kk B-frag: 1 transient reg set
        bf16x8 b = *(const bf16x8*)(lds + bufR + rb[kk] + nt*4096);
        acc[0] = __builtin_amdgcn_mfma_f32_16x16x32_bf16(afr[0][kk], b, acc[0], 0,0,0);
        acc[1] = __builtin_amdgcn_mfma_f32_16x16x32_bf16(afr[1][kk], b, acc[1], 0,0,0);
        acc[2] = __builtin_amdgcn_mfma_f32_16x16x32_bf16(afr[2][kk], b, acc[2], 0,0,0);
        acc[3] = __builtin_amdgcn_mfma_f32_16x16x32_bf16(afr[3][kk], b, acc[3], 0,0,0);
      }
      float hv[4];
      #pragma unroll
      for (int q=0;q<4;++q){          // gates: i,f,g,o
        float zi=acc[0][q], zf=acc[1][q], zg=acc[2][q], zo=acc[3][q];
        float cn = sigm(zf)*creg[nt][q] + sigm(zi)*tanh_(zg);
        creg[nt][q] = cn;
        hv[q] = sigm(zo)*tanh_(cn);
      }
      u32 plo, phi;
      asm("v_cvt_pk_bf16_f32 %0, %1, %2" : "=v"(plo) : "v"(hv[0]), "v"(hv[1]));
      asm("v_cvt_pk_bf16_f32 %0, %1, %2" : "=v"(phi) : "v"(hv[2]), "v"(hv[3]));
      uint2 hw; hw.x = plo; hw.y = phi;
      *(uint2*)(lds + bufW + wbB + nt*4096) = hw;
    }
    __syncthreads();
  }
  // fc epilogue: final h in buffer 0; wave -> (node tile = wave>>2, out tile = wave&3)
  const int ntE = wave>>2, ot = wave&3;
  f32x4 fca;
  fca[0]=0.f; fca[1]=0.f; fca[2]=0.f; fca[3]=0.f;
  #pragma unroll
  for (int kk=0;kk<4;++kk){
    bf16x8 b = *(const bf16x8*)(lds + rb[kk] + ntE*4096);
    const float* fr = fc_w + (ot*16 + c16)*128 + kk*32 + g4*8;
    f32x4 wa = *(const f32x4*)fr;
    f32x4 wbv = *(const f32x4*)(fr+4);
    bf16x8 a;
    a[0]=(short)f2bf(wa[0]); a[1]=(short)f2bf(wa[1]);
    a[2]=(short)f2bf(wa[2]); a[3]=(short)f2bf(wa[3]);
    a[4]=(short)f2bf(wbv[0]); a[5]=(short)f2bf(wbv[1]);
    a[6]=(short)f2bf(wbv[2]); a[7]=(short)f2bf(wbv[3]);
    fca = __builtin_amdgcn_mfma_f32_16x16x32_bf16(a, b, fca, 0,0,0);
  }
  const int node = nb + ntE*16 + c16;
  if (node < N_NODES){
    #pragma unroll
    for (int q=0;q<4;++q){
      int o = ot*16 + g4*4 + q;
      feats[node*64 + o] = fca[q] + fc_b[o];
    }
  }
}

// ---------------------------------------------------------------------------
// CSR build: histogram -> block scan -> bucket permutation
// ---------------------------------------------------------------------------
__global__ __launch_bounds__(256) void hist_kernel(
    const int* __restrict__ dst, int* __restrict__ cnt, int n)
{
  int e = blockIdx.x*256 + threadIdx.x;
  if (e < n) atomicAdd(&cnt[dst[e]], 1);
}

__global__ __launch_bounds__(1024) void scan_kernel(
    int* __restrict__ cnt, int* __restrict__ ofs)   // cnt doubles as "cur"
{
  __shared__ int sums[1024];
  const int tid = threadIdx.x;
  const int base = tid*30;                          // 1024*30 = 30720 >= 30001
  int loc[30]; int s = 0;
  #pragma unroll
  for (int i=0;i<30;++i){
    int d = base + i;
    int c = (d < N_NODES) ? cnt[d] : 0;
    loc[i] = s; s += c;
  }
  sums[tid] = s;
  __syncthreads();
  for (int off=1; off<1024; off<<=1){
    int v = (tid >= off) ? sums[tid-off] : 0;
    __syncthreads();
    sums[tid] += v;
    __syncthreads();
  }
  int excl = sums[tid] - s;
  #pragma unroll
  for (int i=0;i<30;++i){
    int d = base + i;
    if (d <= N_NODES){
      int v = excl + loc[i];
      ofs[d] = v;
      if (d < N_NODES) cnt[d] = v;                  // reset cur = segment start
    }
  }
}

__global__ __launch_bounds__(256) void permute_kernel(
    const int* __restrict__ dst, int* __restrict__ cur,
    int* __restrict__ perm, int n)
{
  int e = blockIdx.x*256 + threadIdx.x;
  if (e < n){
    int p = atomicAdd(&cur[dst[e]], 1);
    perm[p] = e;
  }
}

// ---------------------------------------------------------------------------
// RGCN transform-first: tmp[n][r*NO+o] = (relu? h[n]) @ W_r   (K=64, f32)
// block 256 thr, tile 64 nodes x 128 cols; grid (469, 8*NO/128)
// ---------------------------------------------------------------------------
template<int NO, bool RELU>
__global__ __launch_bounds__(256) void transform_kernel(
    const float* __restrict__ h, const float* __restrict__ W,
    float* __restrict__ tmp, int n_nodes)
{
  __shared__ float As[64][68];
  __shared__ float Bs[64][132];
  const int tid = threadIdx.x;
  const int n0 = blockIdx.x*64;
  const int j0 = blockIdx.y*128;
  constexpr int WIDTH = 8*NO;

  for (int idx = tid*4; idx < 4096; idx += 1024){
    int r = idx>>6, c = idx&63;
    int n = n0 + r; if (n > n_nodes-1) n = n_nodes-1;
    f32x4 v = *(const f32x4*)(h + (size_t)n*64 + c);
    if (RELU){
      v[0]=fmaxf(v[0],0.f); v[1]=fmaxf(v[1],0.f);
      v[2]=fmaxf(v[2],0.f); v[3]=fmaxf(v[3],0.f);
    }
    *(f32x4*)&As[r][c] = v;
  }
  for (int idx = tid*4; idx < 8192; idx += 1024){
    int k = idx>>7, j = idx&127;
    int jj = j0 + j;
    int r = jj / NO, o = jj & (NO-1);
    f32x4 v = *(const f32x4*)(W + r*(64*NO) + k*NO + o);
    *(f32x4*)&Bs[k][j] = v;
  }
  __syncthreads();

  const int tx = tid&15, ty = tid>>4;   // 8 cols x 4 nodes per thread
  float acc[4][8];
  #pragma unroll
  for (int i=0;i<4;++i)
    #pragma unroll
    for (int j=0;j<8;++j) acc[i][j]=0.f;

  #pragma unroll 4
  for (int k=0;k<64;++k){
    f32x4 b0 = *(const f32x4*)&Bs[k][tx*8];
    f32x4 b1 = *(const f32x4*)&Bs[k][tx*8+4];
    #pragma unroll
    for (int i=0;i<4;++i){
      float a = As[ty*4+i][k];
      #pragma unroll
      for (int j=0;j<4;++j){
        acc[i][j]   += a*b0[j];
        acc[i][j+4] += a*b1[j];
      }
    }
  }
  #pragma unroll
  for (int i=0;i<4;++i){
    int n = n0 + ty*4 + i;
    if (n < n_nodes){
      *(f32x4*)(tmp + (size_t)n*WIDTH + j0 + tx*8)     = *(f32x4*)&acc[i][0];
      *(f32x4*)(tmp + (size_t)n*WIDTH + j0 + tx*8 + 4) = *(f32x4*)&acc[i][4];
    }
  }
}

// ---------------------------------------------------------------------------
// CSR gather-reduce: out[d][:NO] = sum over edges e with dst==d of
//   enorm[e] * tmp[src[e]][rel[e]][:NO]      (no atomics, coalesced writes)
// NO=64: wave per dst.  NO=16: 4 dsts per wave (16-lane groups).
// ---------------------------------------------------------------------------
template<int NO>
__global__ __launch_bounds__(256) void gather_kernel(
    const float* __restrict__ tmp, const int* __restrict__ perm,
    const int* __restrict__ ofs, const int* __restrict__ src,
    const int* __restrict__ rel, const float* __restrict__ enorm,
    float* __restrict__ out)
{
  constexpr int WIDTH = 8*NO;
  const int lane = threadIdx.x & 63;
  const int wid = (blockIdx.x*256 + threadIdx.x) >> 6;
  int d, o;
  if (NO == 64){ d = wid; o = lane; }
  else         { d = wid*4 + (lane>>4); o = lane & 15; }
  if (d >= N_NODES) return;
  const int beg = ofs[d], end = ofs[d+1];
  float acc = 0.f;
  if (beg < end){
    int pe = perm[beg];
    int s = src[pe], r = rel[pe]; float nm = enorm[pe];
    for (int i = beg; i < end; ){
      float v = tmp[(size_t)s*WIDTH + r*NO + o];
      ++i;
      int s1=0, r1=0; float nm1=0.f;
      if (i < end){
        int pe1 = perm[i];
        s1 = src[pe1]; r1 = rel[pe1]; nm1 = enorm[pe1];
      }
      acc += nm * v;
      s = s1; r = r1; nm = nm1;
    }
  }
  out[(size_t)d*NO + o] = acc;
}

// ---------------------------------------------------------------------------
extern "C" void kernel_launch(void* const* d_in, const int* in_sizes, int n_in,
                              void* d_out, int out_size, void* d_ws, size_t ws_size,
                              hipStream_t stream)
{
  const int*   tok    = (const int*)  d_in[0];
  const int*   src    = (const int*)  d_in[2];
  const int*   dst    = (const int*)  d_in[3];
  const int*   rel    = (const int*)  d_in[4];
  const float* enorm  = (const float*)d_in[5];
  const float* emb    = (const float*)d_in[6];
  const float* w_ih   = (const float*)d_in[7];
  const float* w_hh   = (const float*)d_in[8];
  const float* b_ih   = (const float*)d_in[9];
  const float* b_hh   = (const float*)d_in[10];
  const float* fc_w   = (const float*)d_in[11];
  const float* fc_b   = (const float*)d_in[12];
  const float* basis0 = (const float*)d_in[13];
  const float* wcomp0 = (const float*)d_in[14];
  const float* basis1 = (const float*)d_in[15];
  const float* wcomp1 = (const float*)d_in[16];
  const float* basis2 = (const float*)d_in[17];
  const float* wcomp2 = (const float*)d_in[18];

  char* ws = (char*)d_ws;
  // tmp [0, 61.44M); eproj overlaps its head (dead before first transform)
  float* tmp   = (float*)(ws);                 // 61,440,000 B
  u16*   eproj = (u16*)  (ws);                 // 10,240,000 B (inside tmp)
  float* feats = (float*)(ws + 61440000);      //  7,680,000 B
  // CSR arrays live in the feats region (feats dead after transform layer 0)
  int*   ofs   = (int*)  (ws + 61440000);      //    120,064 B
  int*   cur   = (int*)  (ws + 61560064);      //    120,064 B
  int*   perm  = (int*)  (ws + 61680128);      //  1,920,000 B (ends 63,600,128)
  float* g1    = (float*)(ws + 69120000);      //  7,680,000 B
  float* g2    = (float*)(ws + 76800000);      //  7,680,000 B
  float* W0    = (float*)(ws + 84480000);      //    131,072 B
  float* W1    = (float*)(ws + 84611072);      //    131,072 B
  float* W2    = (float*)(ws + 84742144);      //     32,768 B

  wmat_kernel<<<288, 256, 0, stream>>>(basis0, wcomp0, basis1, wcomp1,
                                       basis2, wcomp2, W0, W1, W2);
  embproj_kernel<<<dim3(157,4), 256, 0, stream>>>(emb, w_ih, b_ih, b_hh, eproj);
  lstm_kernel<<<938, 512, 0, stream>>>(tok, eproj, w_hh, fc_w, fc_b, feats);

  // layer 0 transform: feats -> tmp (feats dead afterwards)
  transform_kernel<64,false><<<dim3(469,4), 256, 0, stream>>>(feats, W0, tmp, N_NODES);

  // CSR build (into the now-dead feats region)
  hipMemsetAsync(cur, 0, 120004, stream);
  hist_kernel<<<1875, 256, 0, stream>>>(dst, cur, N_EDGES);
  scan_kernel<<<1, 1024, 0, stream>>>(cur, ofs);
  permute_kernel<<<1875, 256, 0, stream>>>(dst, cur, perm, N_EDGES);

  // layer 0 gather: tmp -> g1
  gather_kernel<64><<<7500, 256, 0, stream>>>(tmp, perm, ofs, src, rel, enorm, g1);

  // layer 1: relu(g1) -> tmp -> g2
  transform_kernel<64,true><<<dim3(469,4), 256, 0, stream>>>(g1, W1, tmp, N_NODES);
  gather_kernel<64><<<7500, 256, 0, stream>>>(tmp, perm, ofs, src, rel, enorm, g2);

  // layer 2: relu(g2) -> tmp -> out
  transform_kernel<16,true><<<dim3(469,1), 256, 0, stream>>>(g2, W2, tmp, N_NODES);
  gather_kernel<16><<<1875, 256, 0, stream>>>(tmp, perm, ofs, src, rel, enorm, (float*)d_out);
}